// Round 9
// baseline (150.690 us; speedup 1.0000x reference)
//
#include <hip/hip_runtime.h>

// Pipeline: prep_w -> qkv_gemm (fused Q,K,V; K & V^T written XOR-swizzled)
//           -> attn (flash; burst mask prologue ballot-packs block's 512KB mask slice
//              into 16KB LDS bit-table; dbuf LDS K/V + counted vmcnt; P relayout via
//              idle V-buffer with XOR swizzle) -> out_gemm
// All matmul compute in bf16 MFMA (16x16x32), f32 accumulate. Output f32.

typedef __attribute__((ext_vector_type(4))) float    f32x4;
typedef __attribute__((ext_vector_type(8))) short    s16x8;
typedef __attribute__((ext_vector_type(4))) short    s16x4;
typedef unsigned long long u64;

__device__ __forceinline__ short f2b(float f) {
    union { float f; unsigned u; } v; v.f = f;
    unsigned r = v.u + 0x7FFFu + ((v.u >> 16) & 1u);
    return (short)(r >> 16);
}

__device__ __forceinline__ void gl_lds16(const short* g, short* l) {
    __builtin_amdgcn_global_load_lds(
        (const __attribute__((address_space(1))) unsigned int*)g,
        (__attribute__((address_space(3))) unsigned int*)l, 16, 0, 0);
}

// ---- Wt[w][n][k] = (bf16) W_w[k][n], w order {q,k,v,o} ----
__global__ void prep_w(const float* __restrict__ Wq, const float* __restrict__ Wk,
                       const float* __restrict__ Wv, const float* __restrict__ Wo,
                       short* __restrict__ Wt) {
    int idx = blockIdx.x * 256 + threadIdx.x;       // 4 * 65536 total
    int w = idx >> 16, rem = idx & 65535;
    int n = rem >> 8, kk = rem & 255;
    const float* W = (w == 0) ? Wq : (w == 1) ? Wk : (w == 2) ? Wv : Wo;
    Wt[idx] = f2b(W[kk * 256 + n]);
}

// ---- fused QKV projection: x[32768,256] f32 @ W^T -> relu -> bf16 ----
// q stored [seq][h] linear; k stored [seq][h] with 16B-chunk low3 XOR (seq&7);
// v stored transposed Vt[b][h][seq] with 16B-chunk low3 XOR (h&7).
__global__ __launch_bounds__(256) void qkv_gemm(
        const float* __restrict__ x, const short* __restrict__ Wt,
        const float* __restrict__ bq, const float* __restrict__ bk, const float* __restrict__ bv,
        short* __restrict__ qO, short* __restrict__ kO, short* __restrict__ vtO) {
    __shared__ short a_lds[128][72];        // x tile bf16 (also reused as epilogue bounce)
    __shared__ short b_lds[3][64][72];      // W^T tiles
    const int tid = threadIdx.x;
    const int bm = blockIdx.x >> 2, bn = blockIdx.x & 3;
    const int s0 = bm * 128, n0 = bn * 64;
    const int wid = tid >> 6, l = tid & 63, lo4 = l & 15, hi4 = l >> 4;
    const int wm = wid >> 1, wn = wid & 1;

    f32x4 acc[3][4][2];
    #pragma unroll
    for (int w = 0; w < 3; ++w)
        #pragma unroll
        for (int mi = 0; mi < 4; ++mi)
            #pragma unroll
            for (int ni = 0; ni < 2; ++ni)
                acc[w][mi][ni] = (f32x4){0.f, 0.f, 0.f, 0.f};

    for (int kt = 0; kt < 4; ++kt) {
        const int k0 = kt * 64;
        #pragma unroll
        for (int i = 0; i < 8; ++i) {                       // stage A: 128x64 f32 -> bf16
            int ch = i * 256 + tid;
            int row = ch >> 4, c4 = (ch & 15) * 4;
            f32x4 xv = *(const f32x4*)(x + (size_t)(s0 + row) * 256 + k0 + c4);
            s16x4 pk = { f2b(xv.x), f2b(xv.y), f2b(xv.z), f2b(xv.w) };
            *(s16x4*)&a_lds[row][c4] = pk;
        }
        #pragma unroll
        for (int w = 0; w < 3; ++w) {                       // stage B: 3 x 64x64 bf16
            #pragma unroll
            for (int i = 0; i < 2; ++i) {
                int ch = i * 256 + tid;
                int n = ch >> 3, c8 = (ch & 7) * 8;
                *(s16x8*)&b_lds[w][n][c8] =
                    *(const s16x8*)(Wt + (size_t)w * 65536 + (size_t)(n0 + n) * 256 + k0 + c8);
            }
        }
        __syncthreads();
        s16x8 af[4][2];
        #pragma unroll
        for (int mi = 0; mi < 4; ++mi)
            #pragma unroll
            for (int kk = 0; kk < 2; ++kk)
                af[mi][kk] = *(s16x8*)&a_lds[wm * 64 + mi * 16 + lo4][kk * 32 + hi4 * 8];
        #pragma unroll
        for (int w = 0; w < 3; ++w)
            #pragma unroll
            for (int ni = 0; ni < 2; ++ni)
                #pragma unroll
                for (int kk = 0; kk < 2; ++kk) {
                    s16x8 bfr = *(s16x8*)&b_lds[w][wn * 32 + ni * 16 + lo4][kk * 32 + hi4 * 8];
                    #pragma unroll
                    for (int mi = 0; mi < 4; ++mi)
                        acc[w][mi][ni] = __builtin_amdgcn_mfma_f32_16x16x32_bf16(
                            af[mi][kk], bfr, acc[w][mi][ni], 0, 0, 0);
                }
        __syncthreads();
    }

    const float* bias[3] = { bq, bk, bv };
    for (int w = 0; w < 3; ++w) {
        #pragma unroll
        for (int mi = 0; mi < 4; ++mi)
            #pragma unroll
            for (int ni = 0; ni < 2; ++ni)
                #pragma unroll
                for (int j = 0; j < 4; ++j) {
                    int r = wm * 64 + mi * 16 + hi4 * 4 + j;
                    int c = wn * 32 + ni * 16 + lo4;
                    float v = acc[w][mi][ni][j] + bias[w][n0 + c];
                    a_lds[r][c] = f2b(fmaxf(v, 0.f));
                }
        __syncthreads();
        if (w == 0) {
            #pragma unroll
            for (int i = 0; i < 4; ++i) {
                int ch = i * 256 + tid;
                int row = ch >> 3, c8 = (ch & 7) * 8;
                *(s16x8*)(qO + (size_t)(s0 + row) * 256 + n0 + c8) = *(s16x8*)&a_lds[row][c8];
            }
        } else if (w == 1) {
            #pragma unroll
            for (int i = 0; i < 4; ++i) {
                int ch = i * 256 + tid;
                int row = ch >> 3, c8 = (ch & 7) * 8;
                int swz = ((c8 >> 3) ^ (row & 7)) * 8;      // seq-keyed chunk XOR
                *(s16x8*)(kO + (size_t)(s0 + row) * 256 + n0 + swz) = *(s16x8*)&a_lds[row][c8];
            }
        } else {
            int bb = s0 >> 10, nn = s0 & 1023;              // block spans a single batch
            #pragma unroll
            for (int i = 0; i < 4; ++i) {
                int ch = i * 256 + tid;
                int h = ch >> 4, sc = (ch & 15) * 8;
                s16x8 t;
                #pragma unroll
                for (int e = 0; e < 8; ++e) t[e] = a_lds[sc + e][h];
                int cil = sc >> 3;                          // 0..15
                int swz = (cil & 8) | ((cil & 7) ^ ((n0 + h) & 7));   // h-keyed chunk XOR
                *(s16x8*)(vtO + ((size_t)bb * 256 + n0 + h) * 1024 + nn + swz * 8) = t;
            }
        }
        __syncthreads();
    }
}

// ---- flash attention: 8 waves/block, Q-tile 128, double-buffered K/V, counted vmcnt ----
// Prologue: each wave ballot-packs its own 16 mask rows (64KB f32) into LDS bit-table
// (word(r,ch,c) at mask_lds[r*16+ch*4+c], bit l = mask[r][ch*256+4l+c]).
// Main loop reads 4 u64/lane/kt from LDS; P relayout goes through vbuf[cur^1] (XOR swz).
__global__ __launch_bounds__(512) void attn(
        const short* __restrict__ q, const short* __restrict__ k,
        const short* __restrict__ vt, const float* __restrict__ mask,
        short* __restrict__ attv) {
    __shared__ short kbuf[2][16384];        // 2 x K[64][256] (row-XOR-swizzled layout)
    __shared__ short vbuf[2][16384];        // 2 x V[256][64] (h-XOR-swizzled layout)
    __shared__ u64 mask_lds[2048];          // [row128][ch4][c4] bit-table (16KB)
    const int tid = threadIdx.x, wid = tid >> 6, l = tid & 63;
    const int lo4 = l & 15, hi4 = l >> 4;
    const int bid = blockIdx.x;
    const int swz = (bid & 7) * 32 + (bid >> 3);    // XCD-chunked: 4 batches per XCD
    const int b = swz >> 3, qb = swz & 7;
    const int q0 = qb * 128 + wid * 16;
    const size_t bq_row = (size_t)b * 1024 + q0;

    const short* kb  = k  + (size_t)b * 1024 * 256;
    const short* vtg = vt + (size_t)b * 256 * 1024;

#define STAGE_K(bufi, c0_) do { const short* sg_ = kb + (size_t)(c0_) * 256;          \
    _Pragma("unroll") for (int i_ = 0; i_ < 4; ++i_) { int cb_ = i_ * 512 + wid * 64; \
        gl_lds16(sg_ + (size_t)(cb_ + l) * 8, &kbuf[bufi][cb_ * 8]); } } while (0)
#define STAGE_V(bufi, c0_) do {                                                       \
    _Pragma("unroll") for (int i_ = 0; i_ < 4; ++i_) { int cb_ = i_ * 512 + wid * 64; \
        int ch_ = cb_ + l; int h_ = ch_ >> 3, cc_ = ch_ & 7;                          \
        gl_lds16(vtg + (size_t)h_ * 1024 + (c0_) + cc_ * 8, &vbuf[bufi][cb_ * 8]); } } while (0)

    // stage tile 0 (completes while the prologue runs)
    STAGE_K(0, 0);
    STAGE_V(0, 0);

    // Q fragments
    s16x8 qf[8];
    {
        const short* qp = q + (bq_row + lo4) * 256 + hi4 * 8;
        #pragma unroll
        for (int t = 0; t < 8; ++t) qf[t] = *(const s16x8*)(qp + t * 32);
    }

    // ---- mask burst prologue: wave packs its 16 rows (64 f32x4 loads, 256 ballots) ----
    {
        const float* mrow = mask + bq_row * 1024 + l * 4;
        #pragma unroll
        for (int g = 0; g < 8; ++g) {
            f32x4 va[8];
            #pragma unroll
            for (int i = 0; i < 8; ++i) {
                int u = g * 8 + i, rr = u >> 2, ch = u & 3;
                va[i] = *(const f32x4*)(mrow + (size_t)rr * 1024 + ch * 256);
            }
            #pragma unroll
            for (int i = 0; i < 8; ++i) {
                int u = g * 8 + i, rr = u >> 2, ch = u & 3;
                u64 b0 = __ballot(va[i].x != 0.f);
                u64 b1 = __ballot(va[i].y != 0.f);
                u64 b2 = __ballot(va[i].z != 0.f);
                u64 b3 = __ballot(va[i].w != 0.f);
                if (l < 4) {
                    u64 bb = (l == 0) ? b0 : (l == 1) ? b1 : (l == 2) ? b2 : b3;
                    mask_lds[(wid * 16 + rr) * 16 + ch * 4 + l] = bb;
                }
            }
        }
    }

    f32x4 oacc[16];
    #pragma unroll
    for (int t = 0; t < 16; ++t) oacc[t] = (f32x4){0.f, 0.f, 0.f, 0.f};
    float m_run[4] = { -1e30f, -1e30f, -1e30f, -1e30f };
    float l_run[4] = { 0.f, 0.f, 0.f, 0.f };
    const int swp = (lo4 & 7) * 8;

    for (int t = 0; t < 16; ++t) {
        const int cur = t & 1;
        const int c0 = t * 64;
        // ---- issue next K stage; wait K[t]+V[t] (counted); publish ----
        if (t < 15) {
            STAGE_K(cur ^ 1, c0 + 64);                      // +4 vmem
            // younger-than-V[t]: K[t+1](4); older K[t],V[t] drained by vmcnt(4)
            asm volatile("s_waitcnt vmcnt(4)" ::: "memory");
        } else {
            asm volatile("s_waitcnt vmcnt(0)" ::: "memory");
        }
        __builtin_amdgcn_s_barrier();
        // ---- QK^T on kbuf[cur] ----
        f32x4 s[4];
        #pragma unroll
        for (int ct = 0; ct < 4; ++ct) s[ct] = (f32x4){0.f, 0.f, 0.f, 0.f};
        __builtin_amdgcn_s_setprio(1);
        #pragma unroll
        for (int ct = 0; ct < 4; ++ct) {
            int row = ct * 16 + lo4, rx = row & 7;
            #pragma unroll
            for (int tt = 0; tt < 8; ++tt) {
                int ch = tt * 4 + hi4;
                int sc = (ch & 24) | ((ch & 7) ^ rx);
                s16x8 kf = *(s16x8*)&kbuf[cur][row * 256 + sc * 8];
                s[ct] = __builtin_amdgcn_mfma_f32_16x16x32_bf16(qf[tt], kf, s[ct], 0, 0, 0);
            }
        }
        __builtin_amdgcn_s_setprio(0);
        // ---- mask words from LDS bit-table ----
        u64 mkc[4];
        #pragma unroll
        for (int j = 0; j < 4; ++j)
            mkc[j] = mask_lds[(wid * 16 + hi4 * 4 + j) * 16 + (t >> 2) * 4 + (lo4 & 3)];
        const unsigned shx = ((unsigned)(t & 3) << 4) | (unsigned)(lo4 >> 2);
        float sm[4][4];
        #pragma unroll
        for (int j = 0; j < 4; ++j) {
            unsigned wsx = (unsigned)(mkc[j] >> shx);
            sm[0][j] = (wsx & 1u)    ? s[0][j] : -1e30f;
            sm[1][j] = (wsx & 16u)   ? s[1][j] : -1e30f;
            sm[2][j] = (wsx & 256u)  ? s[2][j] : -1e30f;
            sm[3][j] = (wsx & 4096u) ? s[3][j] : -1e30f;
        }
        float scale[4], p[4][4];
        #pragma unroll
        for (int j = 0; j < 4; ++j) {
            float tmx = fmaxf(fmaxf(sm[0][j], sm[1][j]), fmaxf(sm[2][j], sm[3][j]));
            tmx = fmaxf(tmx, __shfl_xor(tmx, 1));
            tmx = fmaxf(tmx, __shfl_xor(tmx, 2));
            tmx = fmaxf(tmx, __shfl_xor(tmx, 4));
            tmx = fmaxf(tmx, __shfl_xor(tmx, 8));
            float mnew = fmaxf(m_run[j], tmx);
            scale[j] = __expf(m_run[j] - mnew);
            m_run[j] = mnew;
            float su = 0.f;
            #pragma unroll
            for (int ct = 0; ct < 4; ++ct) { p[ct][j] = __expf(sm[ct][j] - mnew); su += p[ct][j]; }
            su += __shfl_xor(su, 1);
            su += __shfl_xor(su, 2);
            su += __shfl_xor(su, 4);
            su += __shfl_xor(su, 8);
            l_run[j] = l_run[j] * scale[j] + su;
        }
        #pragma unroll
        for (int tt = 0; tt < 16; ++tt)
            #pragma unroll
            for (int j = 0; j < 4; ++j) oacc[tt][j] *= scale[j];
        // ---- P (D-layout) -> vbuf[cur^1] (XOR-swizzled) -> A-fragment ----
        short* pb = &vbuf[cur ^ 1][wid * 1024];
        #pragma unroll
        for (int ct = 0; ct < 4; ++ct)
            #pragma unroll
            for (int j = 0; j < 4; ++j) {
                int r = hi4 * 4 + j;
                pb[r * 64 + ((ct * 16 + lo4) ^ ((r & 7) * 8))] = f2b(p[ct][j]);
            }
        asm volatile("s_waitcnt lgkmcnt(0)" ::: "memory");
        __builtin_amdgcn_sched_barrier(0);
        s16x8 pa0 = *(s16x8*)&pb[lo4 * 64 + ((hi4 * 8) ^ swp)];
        s16x8 pa1 = *(s16x8*)&pb[lo4 * 64 + ((32 + hi4 * 8) ^ swp)];
        asm volatile("s_waitcnt lgkmcnt(0)" ::: "memory");  // pa data landed in regs
        __builtin_amdgcn_s_barrier();                       // block-wide: pa-reads done
        // ---- issue next V stage into the buffer P just vacated ----
        if (t < 15) STAGE_V(cur ^ 1, c0 + 64);              // +4 vmem
        // ---- PV on vbuf[cur] ----
        __builtin_amdgcn_s_setprio(1);
        #pragma unroll
        for (int nt = 0; nt < 16; ++nt) {
            int h = nt * 16 + lo4, hx = h & 7;
            s16x8 vf0 = *(s16x8*)&vbuf[cur][h * 64 + (hi4 ^ hx) * 8];
            s16x8 vf1 = *(s16x8*)&vbuf[cur][h * 64 + ((hi4 + 4) ^ hx) * 8];
            oacc[nt] = __builtin_amdgcn_mfma_f32_16x16x32_bf16(pa0, vf0, oacc[nt], 0, 0, 0);
            oacc[nt] = __builtin_amdgcn_mfma_f32_16x16x32_bf16(pa1, vf1, oacc[nt], 0, 0, 0);
        }
        __builtin_amdgcn_s_setprio(0);
    }
    // ---- epilogue: normalize, bf16, coalesced store via vbuf[0] bounce (4 passes) ----
    float inv[4];
    #pragma unroll
    for (int j = 0; j < 4; ++j) inv[j] = 1.f / l_run[j];
    short* pbE = &vbuf[0][wid * 1024];
    #pragma unroll
    for (int g = 0; g < 4; ++g) {
        asm volatile("s_waitcnt lgkmcnt(0)" ::: "memory");  // prior pass reads done
        #pragma unroll
        for (int ntl = 0; ntl < 4; ++ntl)
            #pragma unroll
            for (int j = 0; j < 4; ++j) {
                int r = hi4 * 4 + j;
                pbE[r * 64 + ((ntl * 16 + lo4) ^ ((r & 7) * 8))] = f2b(oacc[g * 4 + ntl][j] * inv[j]);
            }
        asm volatile("s_waitcnt lgkmcnt(0)" ::: "memory");
        __builtin_amdgcn_sched_barrier(0);
        s16x8 r0 = *(s16x8*)&pbE[lo4 * 64 + ((hi4 * 16) ^ swp)];
        s16x8 r1 = *(s16x8*)&pbE[lo4 * 64 + ((hi4 * 16 + 8) ^ swp)];
        short* op = attv + (bq_row + lo4) * 256 + g * 64 + hi4 * 16;
        *(s16x8*)op = r0;
        *(s16x8*)(op + 8) = r1;
    }
#undef STAGE_K
#undef STAGE_V
}

// ---- output GEMM: attv bf16 @ Wo^T + bo -> relu -> f32 ----
__global__ __launch_bounds__(256) void out_gemm(
        const short* __restrict__ a, const short* __restrict__ Wto,
        const float* __restrict__ bo, float* __restrict__ out) {
    __shared__ short a_lds[128][72];
    __shared__ short b_lds[64][72];
    __shared__ float bounce[128][68];
    const int tid = threadIdx.x;
    const int bm = blockIdx.x >> 2, bn = blockIdx.x & 3;
    const int s0 = bm * 128, n0 = bn * 64;
    const int wid = tid >> 6, l = tid & 63, lo4 = l & 15, hi4 = l >> 4;
    const int wm = wid >> 1, wn = wid & 1;
    f32x4 acc[4][2];
    #pragma unroll
    for (int mi = 0; mi < 4; ++mi)
        #pragma unroll
        for (int ni = 0; ni < 2; ++ni) acc[mi][ni] = (f32x4){0.f, 0.f, 0.f, 0.f};

    for (int kt = 0; kt < 4; ++kt) {
        const int k0 = kt * 64;
        #pragma unroll
        for (int i = 0; i < 4; ++i) {
            int ch = i * 256 + tid;
            int row = ch >> 3, c8 = (ch & 7) * 8;
            *(s16x8*)&a_lds[row][c8] = *(const s16x8*)(a + (size_t)(s0 + row) * 256 + k0 + c8);
        }
        #pragma unroll
        for (int i = 0; i < 2; ++i) {
            int ch = i * 256 + tid;
            int n = ch >> 3, c8 = (ch & 7) * 8;
            *(s16x8*)&b_lds[n][c8] = *(const s16x8*)(Wto + (size_t)(n0 + n) * 256 + k0 + c8);
        }
        __syncthreads();
        s16x8 af[4][2];
        #pragma unroll
        for (int mi = 0; mi < 4; ++mi)
            #pragma unroll
            for (int kk = 0; kk < 2; ++kk)
                af[mi][kk] = *(s16x8*)&a_lds[wm * 64 + mi * 16 + lo4][kk * 32 + hi4 * 8];
        #pragma unroll
        for (int ni = 0; ni < 2; ++ni)
            #pragma unroll
            for (int kk = 0; kk < 2; ++kk) {
                s16x8 bfr = *(s16x8*)&b_lds[wn * 32 + ni * 16 + lo4][kk * 32 + hi4 * 8];
                #pragma unroll
                for (int mi = 0; mi < 4; ++mi)
                    acc[mi][ni] = __builtin_amdgcn_mfma_f32_16x16x32_bf16(
                        af[mi][kk], bfr, acc[mi][ni], 0, 0, 0);
            }
        __syncthreads();
    }
    #pragma unroll
    for (int mi = 0; mi < 4; ++mi)
        #pragma unroll
        for (int ni = 0; ni < 2; ++ni)
            #pragma unroll
            for (int j = 0; j < 4; ++j) {
                int r = wm * 64 + mi * 16 + hi4 * 4 + j;
                int c = wn * 32 + ni * 16 + lo4;
                bounce[r][c] = fmaxf(acc[mi][ni][j] + bo[n0 + c], 0.f);
            }
    __syncthreads();
    #pragma unroll
    for (int i = 0; i < 8; ++i) {
        int ch = i * 256 + tid;
        int row = ch >> 4, c4 = (ch & 15) * 4;
        *(f32x4*)(out + (size_t)(s0 + row) * 256 + n0 + c4) = *(f32x4*)&bounce[row][c4];
    }
}

extern "C" void kernel_launch(void* const* d_in, const int* in_sizes, int n_in,
                              void* d_out, int out_size, void* d_ws, size_t ws_size,
                              hipStream_t stream) {
    const float* x    = (const float*)d_in[0];
    const float* mask = (const float*)d_in[1];
    const float* Wv   = (const float*)d_in[2];
    const float* bv   = (const float*)d_in[3];
    const float* Wk   = (const float*)d_in[4];
    const float* bk   = (const float*)d_in[5];
    const float* Wq   = (const float*)d_in[6];
    const float* bq   = (const float*)d_in[7];
    const float* Wo   = (const float*)d_in[8];
    const float* bo   = (const float*)d_in[9];
    float* out = (float*)d_out;

    char* ws = (char*)d_ws;
    short* Wt   = (short*)ws;                                 // 512 KB @ 0
    short* qB   = (short*)(ws + (1 << 20));                   // 16 MB @ 1 MB
    short* kB   = qB  + (size_t)32768 * 256;                  // @ 17 MB
    short* vtB  = kB  + (size_t)32768 * 256;                  // @ 33 MB
    short* avB  = vtB + (size_t)32768 * 256;                  // @ 49 MB (ends 65 MB)
    (void)in_sizes; (void)n_in; (void)out_size; (void)ws_size;

    prep_w<<<1024, 256, 0, stream>>>(Wq, Wk, Wv, Wo, Wt);
    qkv_gemm<<<1024, 256, 0, stream>>>(x, Wt, bq, bk, bv, qB, kB, vtB);
    attn<<<256, 512, 0, stream>>>(qB, kB, vtB, mask, avB);
    out_gemm<<<1024, 256, 0, stream>>>(avB, Wt + 3 * 65536, bo, out);
}

// Round 10
// 147.863 us; speedup vs baseline: 1.0191x; 1.0191x over previous
//
#include <hip/hip_runtime.h>

// Pipeline: prep_w -> qkv_gemm (fused Q,K,V; K & V^T written XOR-swizzled)
//           -> attn (flash, producer-consumer: 8 compute waves + 4 mask-producer waves;
//              dbuf LDS K/V + counted vmcnt; mask ballot-packed into dbuf LDS bit-table
//              one tile ahead by producers) -> out_gemm
// All matmul compute in bf16 MFMA (16x16x32), f32 accumulate. Output f32.

typedef __attribute__((ext_vector_type(4))) float    f32x4;
typedef __attribute__((ext_vector_type(8))) short    s16x8;
typedef __attribute__((ext_vector_type(4))) short    s16x4;
typedef unsigned long long u64;

__device__ __forceinline__ short f2b(float f) {
    union { float f; unsigned u; } v; v.f = f;
    unsigned r = v.u + 0x7FFFu + ((v.u >> 16) & 1u);
    return (short)(r >> 16);
}

__device__ __forceinline__ void gl_lds16(const short* g, short* l) {
    __builtin_amdgcn_global_load_lds(
        (const __attribute__((address_space(1))) unsigned int*)g,
        (__attribute__((address_space(3))) unsigned int*)l, 16, 0, 0);
}

// ---- Wt[w][n][k] = (bf16) W_w[k][n], w order {q,k,v,o} ----
__global__ void prep_w(const float* __restrict__ Wq, const float* __restrict__ Wk,
                       const float* __restrict__ Wv, const float* __restrict__ Wo,
                       short* __restrict__ Wt) {
    int idx = blockIdx.x * 256 + threadIdx.x;       // 4 * 65536 total
    int w = idx >> 16, rem = idx & 65535;
    int n = rem >> 8, kk = rem & 255;
    const float* W = (w == 0) ? Wq : (w == 1) ? Wk : (w == 2) ? Wv : Wo;
    Wt[idx] = f2b(W[kk * 256 + n]);
}

// ---- fused QKV projection: x[32768,256] f32 @ W^T -> relu -> bf16 ----
// q stored [seq][h] linear; k stored [seq][h] with 16B-chunk low3 XOR (seq&7);
// v stored transposed Vt[b][h][seq] with 16B-chunk low3 XOR (h&7).
__global__ __launch_bounds__(256) void qkv_gemm(
        const float* __restrict__ x, const short* __restrict__ Wt,
        const float* __restrict__ bq, const float* __restrict__ bk, const float* __restrict__ bv,
        short* __restrict__ qO, short* __restrict__ kO, short* __restrict__ vtO) {
    __shared__ short a_lds[128][72];        // x tile bf16 (also reused as epilogue bounce)
    __shared__ short b_lds[3][64][72];      // W^T tiles
    const int tid = threadIdx.x;
    const int bm = blockIdx.x >> 2, bn = blockIdx.x & 3;
    const int s0 = bm * 128, n0 = bn * 64;
    const int wid = tid >> 6, l = tid & 63, lo4 = l & 15, hi4 = l >> 4;
    const int wm = wid >> 1, wn = wid & 1;

    f32x4 acc[3][4][2];
    #pragma unroll
    for (int w = 0; w < 3; ++w)
        #pragma unroll
        for (int mi = 0; mi < 4; ++mi)
            #pragma unroll
            for (int ni = 0; ni < 2; ++ni)
                acc[w][mi][ni] = (f32x4){0.f, 0.f, 0.f, 0.f};

    for (int kt = 0; kt < 4; ++kt) {
        const int k0 = kt * 64;
        #pragma unroll
        for (int i = 0; i < 8; ++i) {                       // stage A: 128x64 f32 -> bf16
            int ch = i * 256 + tid;
            int row = ch >> 4, c4 = (ch & 15) * 4;
            f32x4 xv = *(const f32x4*)(x + (size_t)(s0 + row) * 256 + k0 + c4);
            s16x4 pk = { f2b(xv.x), f2b(xv.y), f2b(xv.z), f2b(xv.w) };
            *(s16x4*)&a_lds[row][c4] = pk;
        }
        #pragma unroll
        for (int w = 0; w < 3; ++w) {                       // stage B: 3 x 64x64 bf16
            #pragma unroll
            for (int i = 0; i < 2; ++i) {
                int ch = i * 256 + tid;
                int n = ch >> 3, c8 = (ch & 7) * 8;
                *(s16x8*)&b_lds[w][n][c8] =
                    *(const s16x8*)(Wt + (size_t)w * 65536 + (size_t)(n0 + n) * 256 + k0 + c8);
            }
        }
        __syncthreads();
        s16x8 af[4][2];
        #pragma unroll
        for (int mi = 0; mi < 4; ++mi)
            #pragma unroll
            for (int kk = 0; kk < 2; ++kk)
                af[mi][kk] = *(s16x8*)&a_lds[wm * 64 + mi * 16 + lo4][kk * 32 + hi4 * 8];
        #pragma unroll
        for (int w = 0; w < 3; ++w)
            #pragma unroll
            for (int ni = 0; ni < 2; ++ni)
                #pragma unroll
                for (int kk = 0; kk < 2; ++kk) {
                    s16x8 bfr = *(s16x8*)&b_lds[w][wn * 32 + ni * 16 + lo4][kk * 32 + hi4 * 8];
                    #pragma unroll
                    for (int mi = 0; mi < 4; ++mi)
                        acc[w][mi][ni] = __builtin_amdgcn_mfma_f32_16x16x32_bf16(
                            af[mi][kk], bfr, acc[w][mi][ni], 0, 0, 0);
                }
        __syncthreads();
    }

    const float* bias[3] = { bq, bk, bv };
    for (int w = 0; w < 3; ++w) {
        #pragma unroll
        for (int mi = 0; mi < 4; ++mi)
            #pragma unroll
            for (int ni = 0; ni < 2; ++ni)
                #pragma unroll
                for (int j = 0; j < 4; ++j) {
                    int r = wm * 64 + mi * 16 + hi4 * 4 + j;
                    int c = wn * 32 + ni * 16 + lo4;
                    float v = acc[w][mi][ni][j] + bias[w][n0 + c];
                    a_lds[r][c] = f2b(fmaxf(v, 0.f));
                }
        __syncthreads();
        if (w == 0) {
            #pragma unroll
            for (int i = 0; i < 4; ++i) {
                int ch = i * 256 + tid;
                int row = ch >> 3, c8 = (ch & 7) * 8;
                *(s16x8*)(qO + (size_t)(s0 + row) * 256 + n0 + c8) = *(s16x8*)&a_lds[row][c8];
            }
        } else if (w == 1) {
            #pragma unroll
            for (int i = 0; i < 4; ++i) {
                int ch = i * 256 + tid;
                int row = ch >> 3, c8 = (ch & 7) * 8;
                int swz = ((c8 >> 3) ^ (row & 7)) * 8;      // seq-keyed chunk XOR
                *(s16x8*)(kO + (size_t)(s0 + row) * 256 + n0 + swz) = *(s16x8*)&a_lds[row][c8];
            }
        } else {
            int bb = s0 >> 10, nn = s0 & 1023;              // block spans a single batch
            #pragma unroll
            for (int i = 0; i < 4; ++i) {
                int ch = i * 256 + tid;
                int h = ch >> 4, sc = (ch & 15) * 8;
                s16x8 t;
                #pragma unroll
                for (int e = 0; e < 8; ++e) t[e] = a_lds[sc + e][h];
                int cil = sc >> 3;                          // 0..15
                int swz = (cil & 8) | ((cil & 7) ^ ((n0 + h) & 7));   // h-keyed chunk XOR
                *(s16x8*)(vtO + ((size_t)bb * 256 + n0 + h) * 1024 + nn + swz * 8) = t;
            }
        }
        __syncthreads();
    }
}

// ---- flash attention, producer-consumer ----
// 12 waves: wid 0..7 compute (16 q-rows each, Q-tile 128); wid 8..11 produce mask bits.
// Producers per kt: load block's 128x64 mask slab coalesced, __ballot-pack into
// B_lds[(t)&1][rg][kk]: bit l of B[rg][kk] = (mask[row rg*4+(l>>4)][col (l&15)*4+kk] != 0).
// Consumer: one ds_read_b64 per lane per kt; bit for (j,ct) = j*16 + ct*4 + (lo4>>2).
// Both roles execute exactly 2 s_barriers per iteration.
__global__ __launch_bounds__(768) void attn(
        const short* __restrict__ q, const short* __restrict__ k,
        const short* __restrict__ vt, const float* __restrict__ mask,
        short* __restrict__ attv) {
    __shared__ short kbuf[2][16384];        // 2 x K[64][256] (row-XOR-swizzled layout)
    __shared__ short vbuf[2][16384];        // 2 x V[256][64] (h-XOR-swizzled layout)
    __shared__ short p_lds[8][16][72];      // per-wave P relayout / epilogue bounce
    __shared__ u64 B_lds[2][32][4];         // mask bit-table dbuf (2KB)
    const int tid = threadIdx.x, wid = tid >> 6, l = tid & 63;
    const int lo4 = l & 15, hi4 = l >> 4;
    const int bid = blockIdx.x;
    const int swz = (bid & 7) * 32 + (bid >> 3);    // XCD-chunked: 4 batches per XCD
    const int b = swz >> 3, qb = swz & 7;
    const size_t bq0 = (size_t)b * 1024 + qb * 128; // block's first q-row (global)

    if (wid >= 8) {
        // ---------------- mask producer waves ----------------
        const int pw = wid - 8;                     // 0..3, rows pw*32..pw*32+32
        const float* mb = mask + (bq0 + pw * 32 + (l >> 4)) * 1024 + (l & 15) * 4;
#define PACK(bufi, c0_) do {                                                   \
        f32x4 va_[8];                                                          \
        _Pragma("unroll") for (int i_ = 0; i_ < 8; ++i_)                       \
            va_[i_] = *(const f32x4*)(mb + (size_t)i_ * 4096 + (c0_));         \
        _Pragma("unroll") for (int i_ = 0; i_ < 8; ++i_) {                     \
            u64 b0_ = __ballot(va_[i_].x != 0.f);                              \
            u64 b1_ = __ballot(va_[i_].y != 0.f);                              \
            u64 b2_ = __ballot(va_[i_].z != 0.f);                              \
            u64 b3_ = __ballot(va_[i_].w != 0.f);                              \
            if (l < 4) {                                                       \
                u64 w_ = (l == 0) ? b0_ : (l == 1) ? b1_ : (l == 2) ? b2_ : b3_; \
                B_lds[bufi][pw * 8 + i_][l] = w_;                              \
            } } } while (0)
        PACK(0, 0);                                 // tile 0 before first barrier
        for (int t = 0; t < 16; ++t) {
            if (t < 15) PACK((t + 1) & 1, (t + 1) * 64);
            asm volatile("s_waitcnt lgkmcnt(0)" ::: "memory");  // publish B writes
            __builtin_amdgcn_s_barrier();           // aligns with compute A(t)
            __builtin_amdgcn_s_barrier();           // aligns with compute B(t)
        }
#undef PACK
        return;
    }

    // ---------------- compute waves ----------------
    const int q0 = qb * 128 + wid * 16;
    const size_t bq_row = (size_t)b * 1024 + q0;
    const short* kb  = k  + (size_t)b * 1024 * 256;
    const short* vtg = vt + (size_t)b * 256 * 1024;

#define STAGE_K(bufi, c0_) do { const short* sg_ = kb + (size_t)(c0_) * 256;          \
    _Pragma("unroll") for (int i_ = 0; i_ < 4; ++i_) { int cb_ = i_ * 512 + wid * 64; \
        gl_lds16(sg_ + (size_t)(cb_ + l) * 8, &kbuf[bufi][cb_ * 8]); } } while (0)
#define STAGE_V(bufi, c0_) do {                                                       \
    _Pragma("unroll") for (int i_ = 0; i_ < 4; ++i_) { int cb_ = i_ * 512 + wid * 64; \
        int ch_ = cb_ + l; int h_ = ch_ >> 3, cc_ = ch_ & 7;                          \
        gl_lds16(vtg + (size_t)h_ * 1024 + (c0_) + cc_ * 8, &vbuf[bufi][cb_ * 8]); } } while (0)

    s16x8 qf[8];
    {
        const short* qp = q + (bq_row + lo4) * 256 + hi4 * 8;
        #pragma unroll
        for (int t = 0; t < 8; ++t) qf[t] = *(const s16x8*)(qp + t * 32);
    }
    // prologue: stage tile 0 (K: 4 loads, V: 4 loads; Q loads are older, drain early)
    STAGE_K(0, 0);
    STAGE_V(0, 0);

    f32x4 oacc[16];
    #pragma unroll
    for (int t = 0; t < 16; ++t) oacc[t] = (f32x4){0.f, 0.f, 0.f, 0.f};
    float m_run[4] = { -1e30f, -1e30f, -1e30f, -1e30f };
    float l_run[4] = { 0.f, 0.f, 0.f, 0.f };

    for (int t = 0; t < 16; ++t) {
        const int cur = t & 1;
        const int c0 = t * 64;
        // ---- issue next K stage, then wait for K[t] (counted) ----
        if (t < 15) {
            STAGE_K(cur ^ 1, c0 + 64);                      // +4 vmem
            // younger-than-K[t]: V[t](4) + K[t+1](4) = 8
            asm volatile("s_waitcnt vmcnt(8)" ::: "memory");
        } else {
            asm volatile("s_waitcnt vmcnt(4)" ::: "memory");
        }
        __builtin_amdgcn_s_barrier();                       // A(t): K[t] + B[t] ready
        // ---- QK^T on kbuf[cur] ----
        f32x4 s[4];
        #pragma unroll
        for (int ct = 0; ct < 4; ++ct) s[ct] = (f32x4){0.f, 0.f, 0.f, 0.f};
        __builtin_amdgcn_s_setprio(1);
        #pragma unroll
        for (int ct = 0; ct < 4; ++ct) {
            int row = ct * 16 + lo4, rx = row & 7;
            #pragma unroll
            for (int tt = 0; tt < 8; ++tt) {
                int ch = tt * 4 + hi4;
                int sc = (ch & 24) | ((ch & 7) ^ rx);
                s16x8 kf = *(s16x8*)&kbuf[cur][row * 256 + sc * 8];
                s[ct] = __builtin_amdgcn_mfma_f32_16x16x32_bf16(qf[tt], kf, s[ct], 0, 0, 0);
            }
        }
        __builtin_amdgcn_s_setprio(0);
        // ---- mask word from LDS bit-table (one ds_read_b64, 16-lane broadcast) ----
        u64 mk = B_lds[t & 1][wid * 4 + hi4][lo4 & 3];
        const unsigned sh0 = (unsigned)(lo4 >> 2);
        float sm[4][4];
        #pragma unroll
        for (int j = 0; j < 4; ++j) {
            unsigned wsx = (unsigned)(mk >> (j * 16 + sh0));
            sm[0][j] = (wsx & 1u)    ? s[0][j] : -1e30f;
            sm[1][j] = (wsx & 16u)   ? s[1][j] : -1e30f;
            sm[2][j] = (wsx & 256u)  ? s[2][j] : -1e30f;
            sm[3][j] = (wsx & 4096u) ? s[3][j] : -1e30f;
        }
        float scale[4], p[4][4];
        #pragma unroll
        for (int j = 0; j < 4; ++j) {
            float tmx = fmaxf(fmaxf(sm[0][j], sm[1][j]), fmaxf(sm[2][j], sm[3][j]));
            tmx = fmaxf(tmx, __shfl_xor(tmx, 1));
            tmx = fmaxf(tmx, __shfl_xor(tmx, 2));
            tmx = fmaxf(tmx, __shfl_xor(tmx, 4));
            tmx = fmaxf(tmx, __shfl_xor(tmx, 8));
            float mnew = fmaxf(m_run[j], tmx);
            scale[j] = __expf(m_run[j] - mnew);
            m_run[j] = mnew;
            float su = 0.f;
            #pragma unroll
            for (int ct = 0; ct < 4; ++ct) { p[ct][j] = __expf(sm[ct][j] - mnew); su += p[ct][j]; }
            su += __shfl_xor(su, 1);
            su += __shfl_xor(su, 2);
            su += __shfl_xor(su, 4);
            su += __shfl_xor(su, 8);
            l_run[j] = l_run[j] * scale[j] + su;
        }
        #pragma unroll
        for (int tt = 0; tt < 16; ++tt)
            #pragma unroll
            for (int j = 0; j < 4; ++j) oacc[tt][j] *= scale[j];
        // ---- P (D-layout) -> per-wave LDS -> A-fragment ----
        #pragma unroll
        for (int ct = 0; ct < 4; ++ct)
            #pragma unroll
            for (int j = 0; j < 4; ++j)
                p_lds[wid][hi4 * 4 + j][ct * 16 + lo4] = f2b(p[ct][j]);
        asm volatile("s_waitcnt lgkmcnt(0)" ::: "memory");
        __builtin_amdgcn_sched_barrier(0);
        s16x8 pa0 = *(s16x8*)&p_lds[wid][lo4][hi4 * 8];
        s16x8 pa1 = *(s16x8*)&p_lds[wid][lo4][32 + hi4 * 8];
        // ---- issue next V stage, then wait for V[t] (counted) ----
        if (t < 15) {
            STAGE_V(cur ^ 1, c0 + 64);                      // +4 vmem
            // younger-than-V[t]: K[t+1](4) + V[t+1](4) = 8
            asm volatile("s_waitcnt vmcnt(8)" ::: "memory");
        } else {
            asm volatile("s_waitcnt vmcnt(0)" ::: "memory");
        }
        __builtin_amdgcn_s_barrier();                       // B(t): V[t] ready
        // ---- PV on vbuf[cur] ----
        __builtin_amdgcn_s_setprio(1);
        #pragma unroll
        for (int nt = 0; nt < 16; ++nt) {
            int h = nt * 16 + lo4, hx = h & 7;
            s16x8 vf0 = *(s16x8*)&vbuf[cur][h * 64 + (hi4 ^ hx) * 8];
            s16x8 vf1 = *(s16x8*)&vbuf[cur][h * 64 + ((hi4 + 4) ^ hx) * 8];
            oacc[nt] = __builtin_amdgcn_mfma_f32_16x16x32_bf16(pa0, vf0, oacc[nt], 0, 0, 0);
            oacc[nt] = __builtin_amdgcn_mfma_f32_16x16x32_bf16(pa1, vf1, oacc[nt], 0, 0, 0);
        }
        __builtin_amdgcn_s_setprio(0);
    }
    // ---- epilogue: normalize, bf16, coalesced store via per-wave LDS (4 passes) ----
    float inv[4];
    #pragma unroll
    for (int j = 0; j < 4; ++j) inv[j] = 1.f / l_run[j];
    #pragma unroll
    for (int g = 0; g < 4; ++g) {
        asm volatile("s_waitcnt lgkmcnt(0)" ::: "memory");  // prior pass reads done
        #pragma unroll
        for (int ntl = 0; ntl < 4; ++ntl)
            #pragma unroll
            for (int j = 0; j < 4; ++j)
                p_lds[wid][hi4 * 4 + j][ntl * 16 + lo4] = f2b(oacc[g * 4 + ntl][j] * inv[j]);
        asm volatile("s_waitcnt lgkmcnt(0)" ::: "memory");
        __builtin_amdgcn_sched_barrier(0);
        s16x8 r0 = *(s16x8*)&p_lds[wid][lo4][hi4 * 16];
        s16x8 r1 = *(s16x8*)&p_lds[wid][lo4][hi4 * 16 + 8];
        short* op = attv + (bq_row + lo4) * 256 + g * 64 + hi4 * 16;
        *(s16x8*)op = r0;
        *(s16x8*)(op + 8) = r1;
    }
#undef STAGE_K
#undef STAGE_V
}

// ---- output GEMM: attv bf16 @ Wo^T + bo -> relu -> f32 ----
__global__ __launch_bounds__(256) void out_gemm(
        const short* __restrict__ a, const short* __restrict__ Wto,
        const float* __restrict__ bo, float* __restrict__ out) {
    __shared__ short a_lds[128][72];
    __shared__ short b_lds[64][72];
    __shared__ float bounce[128][68];
    const int tid = threadIdx.x;
    const int bm = blockIdx.x >> 2, bn = blockIdx.x & 3;
    const int s0 = bm * 128, n0 = bn * 64;
    const int wid = tid >> 6, l = tid & 63, lo4 = l & 15, hi4 = l >> 4;
    const int wm = wid >> 1, wn = wid & 1;
    f32x4 acc[4][2];
    #pragma unroll
    for (int mi = 0; mi < 4; ++mi)
        #pragma unroll
        for (int ni = 0; ni < 2; ++ni) acc[mi][ni] = (f32x4){0.f, 0.f, 0.f, 0.f};

    for (int kt = 0; kt < 4; ++kt) {
        const int k0 = kt * 64;
        #pragma unroll
        for (int i = 0; i < 4; ++i) {
            int ch = i * 256 + tid;
            int row = ch >> 3, c8 = (ch & 7) * 8;
            *(s16x8*)&a_lds[row][c8] = *(const s16x8*)(a + (size_t)(s0 + row) * 256 + k0 + c8);
        }
        #pragma unroll
        for (int i = 0; i < 2; ++i) {
            int ch = i * 256 + tid;
            int n = ch >> 3, c8 = (ch & 7) * 8;
            *(s16x8*)&b_lds[n][c8] = *(const s16x8*)(Wto + (size_t)(n0 + n) * 256 + k0 + c8);
        }
        __syncthreads();
        s16x8 af[4][2];
        #pragma unroll
        for (int mi = 0; mi < 4; ++mi)
            #pragma unroll
            for (int kk = 0; kk < 2; ++kk)
                af[mi][kk] = *(s16x8*)&a_lds[wm * 64 + mi * 16 + lo4][kk * 32 + hi4 * 8];
        #pragma unroll
        for (int ni = 0; ni < 2; ++ni)
            #pragma unroll
            for (int kk = 0; kk < 2; ++kk) {
                s16x8 bfr = *(s16x8*)&b_lds[wn * 32 + ni * 16 + lo4][kk * 32 + hi4 * 8];
                #pragma unroll
                for (int mi = 0; mi < 4; ++mi)
                    acc[mi][ni] = __builtin_amdgcn_mfma_f32_16x16x32_bf16(
                        af[mi][kk], bfr, acc[mi][ni], 0, 0, 0);
            }
        __syncthreads();
    }
    #pragma unroll
    for (int mi = 0; mi < 4; ++mi)
        #pragma unroll
        for (int ni = 0; ni < 2; ++ni)
            #pragma unroll
            for (int j = 0; j < 4; ++j) {
                int r = wm * 64 + mi * 16 + hi4 * 4 + j;
                int c = wn * 32 + ni * 16 + lo4;
                bounce[r][c] = fmaxf(acc[mi][ni][j] + bo[n0 + c], 0.f);
            }
    __syncthreads();
    #pragma unroll
    for (int i = 0; i < 8; ++i) {
        int ch = i * 256 + tid;
        int row = ch >> 4, c4 = (ch & 15) * 4;
        *(f32x4*)(out + (size_t)(s0 + row) * 256 + n0 + c4) = *(f32x4*)&bounce[row][c4];
    }
}

extern "C" void kernel_launch(void* const* d_in, const int* in_sizes, int n_in,
                              void* d_out, int out_size, void* d_ws, size_t ws_size,
                              hipStream_t stream) {
    const float* x    = (const float*)d_in[0];
    const float* mask = (const float*)d_in[1];
    const float* Wv   = (const float*)d_in[2];
    const float* bv   = (const float*)d_in[3];
    const float* Wk   = (const float*)d_in[4];
    const float* bk   = (const float*)d_in[5];
    const float* Wq   = (const float*)d_in[6];
    const float* bq   = (const float*)d_in[7];
    const float* Wo   = (const float*)d_in[8];
    const float* bo   = (const float*)d_in[9];
    float* out = (float*)d_out;

    char* ws = (char*)d_ws;
    short* Wt   = (short*)ws;                                 // 512 KB @ 0
    short* qB   = (short*)(ws + (1 << 20));                   // 16 MB @ 1 MB
    short* kB   = qB  + (size_t)32768 * 256;                  // @ 17 MB
    short* vtB  = kB  + (size_t)32768 * 256;                  // @ 33 MB
    short* avB  = vtB + (size_t)32768 * 256;                  // @ 49 MB (ends 65 MB)
    (void)in_sizes; (void)n_in; (void)out_size; (void)ws_size;

    prep_w<<<1024, 256, 0, stream>>>(Wq, Wk, Wv, Wo, Wt);
    qkv_gemm<<<1024, 256, 0, stream>>>(x, Wt, bq, bk, bv, qB, kB, vtB);
    attn<<<256, 768, 0, stream>>>(qB, kB, vtB, mask, avB);
    out_gemm<<<1024, 256, 0, stream>>>(avB, Wt + 3 * 65536, bo, out);
}

// Round 11
// 141.735 us; speedup vs baseline: 1.0632x; 1.0432x over previous
//
#include <hip/hip_runtime.h>

// Pipeline: prep_w -> qkv_gemm (fused Q,K,V; K & V^T written XOR-swizzled)
//           -> attn (flash, producer-consumer: 8 compute waves + 4 mask-producer waves;
//              producers issue loads 2 tiles ahead and ballot them one phase later, so
//              HBM latency hides under compute and barriers never wait on drains)
//           -> out_gemm
// All matmul compute in bf16 MFMA (16x16x32), f32 accumulate. Output f32.

typedef __attribute__((ext_vector_type(4))) float    f32x4;
typedef __attribute__((ext_vector_type(8))) short    s16x8;
typedef __attribute__((ext_vector_type(4))) short    s16x4;
typedef unsigned long long u64;

__device__ __forceinline__ short f2b(float f) {
    union { float f; unsigned u; } v; v.f = f;
    unsigned r = v.u + 0x7FFFu + ((v.u >> 16) & 1u);
    return (short)(r >> 16);
}

__device__ __forceinline__ void gl_lds16(const short* g, short* l) {
    __builtin_amdgcn_global_load_lds(
        (const __attribute__((address_space(1))) unsigned int*)g,
        (__attribute__((address_space(3))) unsigned int*)l, 16, 0, 0);
}

// ---- Wt[w][n][k] = (bf16) W_w[k][n], w order {q,k,v,o} ----
__global__ void prep_w(const float* __restrict__ Wq, const float* __restrict__ Wk,
                       const float* __restrict__ Wv, const float* __restrict__ Wo,
                       short* __restrict__ Wt) {
    int idx = blockIdx.x * 256 + threadIdx.x;       // 4 * 65536 total
    int w = idx >> 16, rem = idx & 65535;
    int n = rem >> 8, kk = rem & 255;
    const float* W = (w == 0) ? Wq : (w == 1) ? Wk : (w == 2) ? Wv : Wo;
    Wt[idx] = f2b(W[kk * 256 + n]);
}

// ---- fused QKV projection: x[32768,256] f32 @ W^T -> relu -> bf16 ----
// q stored [seq][h] linear; k stored [seq][h] with 16B-chunk low3 XOR (seq&7);
// v stored transposed Vt[b][h][seq] with 16B-chunk low3 XOR (h&7).
__global__ __launch_bounds__(256) void qkv_gemm(
        const float* __restrict__ x, const short* __restrict__ Wt,
        const float* __restrict__ bq, const float* __restrict__ bk, const float* __restrict__ bv,
        short* __restrict__ qO, short* __restrict__ kO, short* __restrict__ vtO) {
    __shared__ short a_lds[128][72];        // x tile bf16 (also reused as epilogue bounce)
    __shared__ short b_lds[3][64][72];      // W^T tiles
    const int tid = threadIdx.x;
    const int bm = blockIdx.x >> 2, bn = blockIdx.x & 3;
    const int s0 = bm * 128, n0 = bn * 64;
    const int wid = tid >> 6, l = tid & 63, lo4 = l & 15, hi4 = l >> 4;
    const int wm = wid >> 1, wn = wid & 1;

    f32x4 acc[3][4][2];
    #pragma unroll
    for (int w = 0; w < 3; ++w)
        #pragma unroll
        for (int mi = 0; mi < 4; ++mi)
            #pragma unroll
            for (int ni = 0; ni < 2; ++ni)
                acc[w][mi][ni] = (f32x4){0.f, 0.f, 0.f, 0.f};

    for (int kt = 0; kt < 4; ++kt) {
        const int k0 = kt * 64;
        #pragma unroll
        for (int i = 0; i < 8; ++i) {                       // stage A: 128x64 f32 -> bf16
            int ch = i * 256 + tid;
            int row = ch >> 4, c4 = (ch & 15) * 4;
            f32x4 xv = *(const f32x4*)(x + (size_t)(s0 + row) * 256 + k0 + c4);
            s16x4 pk = { f2b(xv.x), f2b(xv.y), f2b(xv.z), f2b(xv.w) };
            *(s16x4*)&a_lds[row][c4] = pk;
        }
        #pragma unroll
        for (int w = 0; w < 3; ++w) {                       // stage B: 3 x 64x64 bf16
            #pragma unroll
            for (int i = 0; i < 2; ++i) {
                int ch = i * 256 + tid;
                int n = ch >> 3, c8 = (ch & 7) * 8;
                *(s16x8*)&b_lds[w][n][c8] =
                    *(const s16x8*)(Wt + (size_t)w * 65536 + (size_t)(n0 + n) * 256 + k0 + c8);
            }
        }
        __syncthreads();
        s16x8 af[4][2];
        #pragma unroll
        for (int mi = 0; mi < 4; ++mi)
            #pragma unroll
            for (int kk = 0; kk < 2; ++kk)
                af[mi][kk] = *(s16x8*)&a_lds[wm * 64 + mi * 16 + lo4][kk * 32 + hi4 * 8];
        #pragma unroll
        for (int w = 0; w < 3; ++w)
            #pragma unroll
            for (int ni = 0; ni < 2; ++ni)
                #pragma unroll
                for (int kk = 0; kk < 2; ++kk) {
                    s16x8 bfr = *(s16x8*)&b_lds[w][wn * 32 + ni * 16 + lo4][kk * 32 + hi4 * 8];
                    #pragma unroll
                    for (int mi = 0; mi < 4; ++mi)
                        acc[w][mi][ni] = __builtin_amdgcn_mfma_f32_16x16x32_bf16(
                            af[mi][kk], bfr, acc[w][mi][ni], 0, 0, 0);
                }
        __syncthreads();
    }

    const float* bias[3] = { bq, bk, bv };
    for (int w = 0; w < 3; ++w) {
        #pragma unroll
        for (int mi = 0; mi < 4; ++mi)
            #pragma unroll
            for (int ni = 0; ni < 2; ++ni)
                #pragma unroll
                for (int j = 0; j < 4; ++j) {
                    int r = wm * 64 + mi * 16 + hi4 * 4 + j;
                    int c = wn * 32 + ni * 16 + lo4;
                    float v = acc[w][mi][ni][j] + bias[w][n0 + c];
                    a_lds[r][c] = f2b(fmaxf(v, 0.f));
                }
        __syncthreads();
        if (w == 0) {
            #pragma unroll
            for (int i = 0; i < 4; ++i) {
                int ch = i * 256 + tid;
                int row = ch >> 3, c8 = (ch & 7) * 8;
                *(s16x8*)(qO + (size_t)(s0 + row) * 256 + n0 + c8) = *(s16x8*)&a_lds[row][c8];
            }
        } else if (w == 1) {
            #pragma unroll
            for (int i = 0; i < 4; ++i) {
                int ch = i * 256 + tid;
                int row = ch >> 3, c8 = (ch & 7) * 8;
                int swz = ((c8 >> 3) ^ (row & 7)) * 8;      // seq-keyed chunk XOR
                *(s16x8*)(kO + (size_t)(s0 + row) * 256 + n0 + swz) = *(s16x8*)&a_lds[row][c8];
            }
        } else {
            int bb = s0 >> 10, nn = s0 & 1023;              // block spans a single batch
            #pragma unroll
            for (int i = 0; i < 4; ++i) {
                int ch = i * 256 + tid;
                int h = ch >> 4, sc = (ch & 15) * 8;
                s16x8 t;
                #pragma unroll
                for (int e = 0; e < 8; ++e) t[e] = a_lds[sc + e][h];
                int cil = sc >> 3;                          // 0..15
                int swz = (cil & 8) | ((cil & 7) ^ ((n0 + h) & 7));   // h-keyed chunk XOR
                *(s16x8*)(vtO + ((size_t)bb * 256 + n0 + h) * 1024 + nn + swz * 8) = t;
            }
        }
        __syncthreads();
    }
}

// ---- flash attention, producer-consumer with latency-hidden producers ----
// 12 waves: wid 0..7 compute (16 q-rows each, Q-tile 128); wid 8..11 produce mask bits.
// Producer wave pw owns rows pw*32..pw*32+31. Per compute iteration t it (a) issues the
// 8 coalesced f32x4 loads for tile t+2 right after barrier A(t), and (b) ballots+stores
// them after barrier B(t) -- the loads have a full compute phase to land, so no drain
// ever blocks a barrier. B[t] is in LDS two barriers before compute reads it.
// Bit layout (validated r10): B[slot][rg][c] bit l = mask[row rg*4+(l>>4)][col (l&15)*4+c].
// Consumer: one ds_read_b64/lane/kt; bit for (j,ct) = j*16 + ct*4 + (lo4>>2).
__global__ __launch_bounds__(768) void attn(
        const short* __restrict__ q, const short* __restrict__ k,
        const short* __restrict__ vt, const float* __restrict__ mask,
        short* __restrict__ attv) {
    __shared__ short kbuf[2][16384];        // 2 x K[64][256] (row-XOR-swizzled layout)
    __shared__ short vbuf[2][16384];        // 2 x V[256][64] (h-XOR-swizzled layout)
    __shared__ short p_lds[8][16][72];      // per-wave P relayout / epilogue bounce
    __shared__ u64 B_lds[4][32][4];         // mask bit-table, 4 rotating slots (4KB)
    const int tid = threadIdx.x, wid = tid >> 6, l = tid & 63;
    const int lo4 = l & 15, hi4 = l >> 4;
    const int bid = blockIdx.x;
    const int swz = (bid & 7) * 32 + (bid >> 3);    // XCD-chunked: 4 batches per XCD
    const int b = swz >> 3, qb = swz & 7;
    const size_t bq0 = (size_t)b * 1024 + qb * 128; // block's first q-row (global)

    if (wid >= 8) {
        // ---------------- mask producer waves ----------------
        const int pw = wid - 8;                     // rows pw*32 .. pw*32+31
        const float* mb = mask + (bq0 + pw * 32 + (l >> 4)) * 1024 + (l & 15) * 4;
        f32x4 va[4], vb[4];
#define PISSUE(BUF, tau, g) do {                                               \
        _Pragma("unroll") for (int i_ = 0; i_ < 4; ++i_)                       \
            BUF[i_] = *(const f32x4*)(mb + (size_t)((g) * 16 + i_ * 4) * 1024  \
                                         + (size_t)(tau) * 64); } while (0)
#define PBALLOT(BUF, tau, g) do {                                              \
        _Pragma("unroll") for (int i_ = 0; i_ < 4; ++i_) {                     \
            u64 b0_ = __ballot(BUF[i_].x != 0.f);                              \
            u64 b1_ = __ballot(BUF[i_].y != 0.f);                              \
            u64 b2_ = __ballot(BUF[i_].z != 0.f);                              \
            u64 b3_ = __ballot(BUF[i_].w != 0.f);                              \
            if (l < 4) {                                                       \
                u64 w_ = (l == 0) ? b0_ : (l == 1) ? b1_ : (l == 2) ? b2_ : b3_; \
                B_lds[(tau) & 3][pw * 8 + (g) * 4 + i_][l] = w_;               \
            } } } while (0)
        // prologue: tiles 0 and 1 packed before the first barrier
        PISSUE(va, 0, 0); PISSUE(vb, 0, 1);
        PBALLOT(va, 0, 0); PBALLOT(vb, 0, 1);
        PISSUE(va, 1, 0); PISSUE(vb, 1, 1);
        PBALLOT(va, 1, 0); PBALLOT(vb, 1, 1);
        asm volatile("s_waitcnt lgkmcnt(0)" ::: "memory");  // publish B[0], B[1]
        for (int t = 0; t < 16; ++t) {
            __builtin_amdgcn_s_barrier();           // A(t)
            if (t < 14) { PISSUE(va, t + 2, 0); PISSUE(vb, t + 2, 1); }  // fire & forget
            __builtin_amdgcn_s_barrier();           // B(t)
            if (t < 14) {
                PBALLOT(va, t + 2, 0); PBALLOT(vb, t + 2, 1);   // data landed during QK
                asm volatile("s_waitcnt lgkmcnt(0)" ::: "memory");
            }
        }
#undef PISSUE
#undef PBALLOT
        return;
    }

    // ---------------- compute waves ----------------
    const int q0 = qb * 128 + wid * 16;
    const size_t bq_row = (size_t)b * 1024 + q0;
    const short* kb  = k  + (size_t)b * 1024 * 256;
    const short* vtg = vt + (size_t)b * 256 * 1024;

#define STAGE_K(bufi, c0_) do { const short* sg_ = kb + (size_t)(c0_) * 256;          \
    _Pragma("unroll") for (int i_ = 0; i_ < 4; ++i_) { int cb_ = i_ * 512 + wid * 64; \
        gl_lds16(sg_ + (size_t)(cb_ + l) * 8, &kbuf[bufi][cb_ * 8]); } } while (0)
#define STAGE_V(bufi, c0_) do {                                                       \
    _Pragma("unroll") for (int i_ = 0; i_ < 4; ++i_) { int cb_ = i_ * 512 + wid * 64; \
        int ch_ = cb_ + l; int h_ = ch_ >> 3, cc_ = ch_ & 7;                          \
        gl_lds16(vtg + (size_t)h_ * 1024 + (c0_) + cc_ * 8, &vbuf[bufi][cb_ * 8]); } } while (0)

    s16x8 qf[8];
    {
        const short* qp = q + (bq_row + lo4) * 256 + hi4 * 8;
        #pragma unroll
        for (int t = 0; t < 8; ++t) qf[t] = *(const s16x8*)(qp + t * 32);
    }
    // prologue: stage tile 0 (K: 4 loads, V: 4 loads; Q loads are older, drain early)
    STAGE_K(0, 0);
    STAGE_V(0, 0);

    f32x4 oacc[16];
    #pragma unroll
    for (int t = 0; t < 16; ++t) oacc[t] = (f32x4){0.f, 0.f, 0.f, 0.f};
    float m_run[4] = { -1e30f, -1e30f, -1e30f, -1e30f };
    float l_run[4] = { 0.f, 0.f, 0.f, 0.f };

    for (int t = 0; t < 16; ++t) {
        const int cur = t & 1;
        const int c0 = t * 64;
        // ---- issue next K stage, then wait for K[t] (counted) ----
        if (t < 15) {
            STAGE_K(cur ^ 1, c0 + 64);                      // +4 vmem
            // younger-than-K[t]: V[t](4) + K[t+1](4) = 8
            asm volatile("s_waitcnt vmcnt(8)" ::: "memory");
        } else {
            asm volatile("s_waitcnt vmcnt(4)" ::: "memory");
        }
        __builtin_amdgcn_s_barrier();                       // A(t): K[t] + B[t] ready
        // ---- QK^T on kbuf[cur] ----
        f32x4 s[4];
        #pragma unroll
        for (int ct = 0; ct < 4; ++ct) s[ct] = (f32x4){0.f, 0.f, 0.f, 0.f};
        __builtin_amdgcn_s_setprio(1);
        #pragma unroll
        for (int ct = 0; ct < 4; ++ct) {
            int row = ct * 16 + lo4, rx = row & 7;
            #pragma unroll
            for (int tt = 0; tt < 8; ++tt) {
                int ch = tt * 4 + hi4;
                int sc = (ch & 24) | ((ch & 7) ^ rx);
                s16x8 kf = *(s16x8*)&kbuf[cur][row * 256 + sc * 8];
                s[ct] = __builtin_amdgcn_mfma_f32_16x16x32_bf16(qf[tt], kf, s[ct], 0, 0, 0);
            }
        }
        __builtin_amdgcn_s_setprio(0);
        // ---- mask word from LDS bit-table (one ds_read_b64, 16-lane broadcast) ----
        u64 mk = B_lds[t & 3][wid * 4 + hi4][lo4 & 3];
        const unsigned sh0 = (unsigned)(lo4 >> 2);
        float sm[4][4];
        #pragma unroll
        for (int j = 0; j < 4; ++j) {
            unsigned wsx = (unsigned)(mk >> (j * 16 + sh0));
            sm[0][j] = (wsx & 1u)    ? s[0][j] : -1e30f;
            sm[1][j] = (wsx & 16u)   ? s[1][j] : -1e30f;
            sm[2][j] = (wsx & 256u)  ? s[2][j] : -1e30f;
            sm[3][j] = (wsx & 4096u) ? s[3][j] : -1e30f;
        }
        float scale[4], p[4][4];
        #pragma unroll
        for (int j = 0; j < 4; ++j) {
            float tmx = fmaxf(fmaxf(sm[0][j], sm[1][j]), fmaxf(sm[2][j], sm[3][j]));
            tmx = fmaxf(tmx, __shfl_xor(tmx, 1));
            tmx = fmaxf(tmx, __shfl_xor(tmx, 2));
            tmx = fmaxf(tmx, __shfl_xor(tmx, 4));
            tmx = fmaxf(tmx, __shfl_xor(tmx, 8));
            float mnew = fmaxf(m_run[j], tmx);
            scale[j] = __expf(m_run[j] - mnew);
            m_run[j] = mnew;
            float su = 0.f;
            #pragma unroll
            for (int ct = 0; ct < 4; ++ct) { p[ct][j] = __expf(sm[ct][j] - mnew); su += p[ct][j]; }
            su += __shfl_xor(su, 1);
            su += __shfl_xor(su, 2);
            su += __shfl_xor(su, 4);
            su += __shfl_xor(su, 8);
            l_run[j] = l_run[j] * scale[j] + su;
        }
        #pragma unroll
        for (int tt = 0; tt < 16; ++tt)
            #pragma unroll
            for (int j = 0; j < 4; ++j) oacc[tt][j] *= scale[j];
        // ---- P (D-layout) -> per-wave LDS -> A-fragment ----
        #pragma unroll
        for (int ct = 0; ct < 4; ++ct)
            #pragma unroll
            for (int j = 0; j < 4; ++j)
                p_lds[wid][hi4 * 4 + j][ct * 16 + lo4] = f2b(p[ct][j]);
        asm volatile("s_waitcnt lgkmcnt(0)" ::: "memory");
        __builtin_amdgcn_sched_barrier(0);
        s16x8 pa0 = *(s16x8*)&p_lds[wid][lo4][hi4 * 8];
        s16x8 pa1 = *(s16x8*)&p_lds[wid][lo4][32 + hi4 * 8];
        // ---- issue next V stage, then wait for V[t] (counted) ----
        if (t < 15) {
            STAGE_V(cur ^ 1, c0 + 64);                      // +4 vmem
            // younger-than-V[t]: K[t+1](4) + V[t+1](4) = 8
            asm volatile("s_waitcnt vmcnt(8)" ::: "memory");
        } else {
            asm volatile("s_waitcnt vmcnt(0)" ::: "memory");
        }
        __builtin_amdgcn_s_barrier();                       // B(t): V[t] ready
        // ---- PV on vbuf[cur] ----
        __builtin_amdgcn_s_setprio(1);
        #pragma unroll
        for (int nt = 0; nt < 16; ++nt) {
            int h = nt * 16 + lo4, hx = h & 7;
            s16x8 vf0 = *(s16x8*)&vbuf[cur][h * 64 + (hi4 ^ hx) * 8];
            s16x8 vf1 = *(s16x8*)&vbuf[cur][h * 64 + ((hi4 + 4) ^ hx) * 8];
            oacc[nt] = __builtin_amdgcn_mfma_f32_16x16x32_bf16(pa0, vf0, oacc[nt], 0, 0, 0);
            oacc[nt] = __builtin_amdgcn_mfma_f32_16x16x32_bf16(pa1, vf1, oacc[nt], 0, 0, 0);
        }
        __builtin_amdgcn_s_setprio(0);
    }
    // ---- epilogue: normalize, bf16, coalesced store via per-wave LDS (4 passes) ----
    float inv[4];
    #pragma unroll
    for (int j = 0; j < 4; ++j) inv[j] = 1.f / l_run[j];
    #pragma unroll
    for (int g = 0; g < 4; ++g) {
        asm volatile("s_waitcnt lgkmcnt(0)" ::: "memory");  // prior pass reads done
        #pragma unroll
        for (int ntl = 0; ntl < 4; ++ntl)
            #pragma unroll
            for (int j = 0; j < 4; ++j)
                p_lds[wid][hi4 * 4 + j][ntl * 16 + lo4] = f2b(oacc[g * 4 + ntl][j] * inv[j]);
        asm volatile("s_waitcnt lgkmcnt(0)" ::: "memory");
        __builtin_amdgcn_sched_barrier(0);
        s16x8 r0 = *(s16x8*)&p_lds[wid][lo4][hi4 * 16];
        s16x8 r1 = *(s16x8*)&p_lds[wid][lo4][hi4 * 16 + 8];
        short* op = attv + (bq_row + lo4) * 256 + g * 64 + hi4 * 16;
        *(s16x8*)op = r0;
        *(s16x8*)(op + 8) = r1;
    }
#undef STAGE_K
#undef STAGE_V
}

// ---- output GEMM: attv bf16 @ Wo^T + bo -> relu -> f32 ----
__global__ __launch_bounds__(256) void out_gemm(
        const short* __restrict__ a, const short* __restrict__ Wto,
        const float* __restrict__ bo, float* __restrict__ out) {
    __shared__ short a_lds[128][72];
    __shared__ short b_lds[64][72];
    __shared__ float bounce[128][68];
    const int tid = threadIdx.x;
    const int bm = blockIdx.x >> 2, bn = blockIdx.x & 3;
    const int s0 = bm * 128, n0 = bn * 64;
    const int wid = tid >> 6, l = tid & 63, lo4 = l & 15, hi4 = l >> 4;
    const int wm = wid >> 1, wn = wid & 1;
    f32x4 acc[4][2];
    #pragma unroll
    for (int mi = 0; mi < 4; ++mi)
        #pragma unroll
        for (int ni = 0; ni < 2; ++ni) acc[mi][ni] = (f32x4){0.f, 0.f, 0.f, 0.f};

    for (int kt = 0; kt < 4; ++kt) {
        const int k0 = kt * 64;
        #pragma unroll
        for (int i = 0; i < 4; ++i) {
            int ch = i * 256 + tid;
            int row = ch >> 3, c8 = (ch & 7) * 8;
            *(s16x8*)&a_lds[row][c8] = *(const s16x8*)(a + (size_t)(s0 + row) * 256 + k0 + c8);
        }
        #pragma unroll
        for (int i = 0; i < 2; ++i) {
            int ch = i * 256 + tid;
            int n = ch >> 3, c8 = (ch & 7) * 8;
            *(s16x8*)&b_lds[n][c8] = *(const s16x8*)(Wto + (size_t)(n0 + n) * 256 + k0 + c8);
        }
        __syncthreads();
        s16x8 af[4][2];
        #pragma unroll
        for (int mi = 0; mi < 4; ++mi)
            #pragma unroll
            for (int kk = 0; kk < 2; ++kk)
                af[mi][kk] = *(s16x8*)&a_lds[wm * 64 + mi * 16 + lo4][kk * 32 + hi4 * 8];
        #pragma unroll
        for (int ni = 0; ni < 2; ++ni)
            #pragma unroll
            for (int kk = 0; kk < 2; ++kk) {
                s16x8 bfr = *(s16x8*)&b_lds[wn * 32 + ni * 16 + lo4][kk * 32 + hi4 * 8];
                #pragma unroll
                for (int mi = 0; mi < 4; ++mi)
                    acc[mi][ni] = __builtin_amdgcn_mfma_f32_16x16x32_bf16(
                        af[mi][kk], bfr, acc[mi][ni], 0, 0, 0);
            }
        __syncthreads();
    }
    #pragma unroll
    for (int mi = 0; mi < 4; ++mi)
        #pragma unroll
        for (int ni = 0; ni < 2; ++ni)
            #pragma unroll
            for (int j = 0; j < 4; ++j) {
                int r = wm * 64 + mi * 16 + hi4 * 4 + j;
                int c = wn * 32 + ni * 16 + lo4;
                bounce[r][c] = fmaxf(acc[mi][ni][j] + bo[n0 + c], 0.f);
            }
    __syncthreads();
    #pragma unroll
    for (int i = 0; i < 8; ++i) {
        int ch = i * 256 + tid;
        int row = ch >> 4, c4 = (ch & 15) * 4;
        *(f32x4*)(out + (size_t)(s0 + row) * 256 + n0 + c4) = *(f32x4*)&bounce[row][c4];
    }
}

extern "C" void kernel_launch(void* const* d_in, const int* in_sizes, int n_in,
                              void* d_out, int out_size, void* d_ws, size_t ws_size,
                              hipStream_t stream) {
    const float* x    = (const float*)d_in[0];
    const float* mask = (const float*)d_in[1];
    const float* Wv   = (const float*)d_in[2];
    const float* bv   = (const float*)d_in[3];
    const float* Wk   = (const float*)d_in[4];
    const float* bk   = (const float*)d_in[5];
    const float* Wq   = (const float*)d_in[6];
    const float* bq   = (const float*)d_in[7];
    const float* Wo   = (const float*)d_in[8];
    const float* bo   = (const float*)d_in[9];
    float* out = (float*)d_out;

    char* ws = (char*)d_ws;
    short* Wt   = (short*)ws;                                 // 512 KB @ 0
    short* qB   = (short*)(ws + (1 << 20));                   // 16 MB @ 1 MB
    short* kB   = qB  + (size_t)32768 * 256;                  // @ 17 MB
    short* vtB  = kB  + (size_t)32768 * 256;                  // @ 33 MB
    short* avB  = vtB + (size_t)32768 * 256;                  // @ 49 MB (ends 65 MB)
    (void)in_sizes; (void)n_in; (void)out_size; (void)ws_size;

    prep_w<<<1024, 256, 0, stream>>>(Wq, Wk, Wv, Wo, Wt);
    qkv_gemm<<<1024, 256, 0, stream>>>(x, Wt, bq, bk, bv, qB, kB, vtB);
    attn<<<256, 768, 0, stream>>>(qB, kB, vtB, mask, avB);
    out_gemm<<<1024, 256, 0, stream>>>(avB, Wt + 3 * 65536, bo, out);
}